// Round 14
// baseline (79.511 us; speedup 1.0000x reference)
//
#include <hip/hip_runtime.h>
#include <hip/hip_bf16.h>

// MicrotubuleAttention — exact algebraic reduction + bf16 MFMA, fused v4.
//
// GTP penalty: (1 - exp(-gamma*dist))*(-1e9), gamma >= 1e-4 => every
// off-diagonal softmax argument <= -9.9e4 => expf underflows to exactly 0.
// Softmax is exactly one-hot at k==q, so attention output == V_rep and
//   out = (x @ Wv) @ Weff        (4.3 GFLOP total)
// with Weff[c][m] = sum_{r=0..3} Wo[(4*(c>>6)+r)*64 + (c&63)][m]  (GQA fold).
// RoPE/Q/K/polarity are dead code.
//
// ONE persistent kernel, 256 blocks (1/CU), 3 phases, relaxed-spin barriers.
// v4 fix vs R13: phase B restored to the VERIFIED K-loop ordering
//   vmcnt(N) -> s_barrier -> stage(t+2) -> compute        (R5/R9 pattern)
// R13's barrier->stage->vmcnt order was a cross-wave race: vmcnt counts only
// the issuing wave's loads, so other waves' LDS writes weren't guaranteed
// resident at ds_read time (absmax 0.97). Triple-buffer depth-2, LP=8 ->
// counted vmcnt(8), 96 KB LDS (1 blk/CU — fine).
//   phase 0: byte-balanced prep (22/14/6 xcvt jobs for plain/WvT/WeffT)
//   phase A: Vb = xb @ WvT^T, 64x64 tiles (R9/R11 verbatim)
//   phase B: out = Vb @ WeffT^T, ONE 128x128 tile/block + LDS-bounce epilogue
// Rule from R6+R12: NO f32->bf16 conversion inside GEMM K-loops.

using bf16x8 = __attribute__((ext_vector_type(8))) short;
using f32x4  = __attribute__((ext_vector_type(4))) float;

static constexpr int DMODEL = 1024;
static constexpr int KVDIM  = 256;   // H_KV * D_HEAD
static constexpr int ROWS   = 4096;  // B * T
static constexpr int NBLK   = 256;

__device__ inline unsigned short f2bf(float f) {
    __hip_bfloat16 h = __float2bfloat16(f);   // RNE
    return *reinterpret_cast<unsigned short*>(&h);
}

// Grid barrier (R11-verified): one atomicAdd arrival per block; RELAXED
// read-only spin; one release fence before arrival, one acquire after exit.
__device__ inline void gbar(unsigned* slot, unsigned target) {
    __syncthreads();                 // drains lanes' stores (vmcnt 0)
    if (threadIdx.x == 0) {
        __threadfence();             // release
        atomicAdd(slot, 1u);
        while (__hip_atomic_load(slot, __ATOMIC_RELAXED,
                                 __HIP_MEMORY_SCOPE_AGENT) < target)
            __builtin_amdgcn_s_sleep(2);
        __threadfence();             // acquire
    }
    __syncthreads();
}

__global__ __launch_bounds__(256) void fused_kernel(
    const float* __restrict__ x,
    const float* __restrict__ Wv,
    const float* __restrict__ Wo,
    unsigned short* __restrict__ xb,
    unsigned short* __restrict__ WvT,
    unsigned short* __restrict__ WeffT,
    unsigned short* __restrict__ Vb,
    float* __restrict__ out,
    unsigned* __restrict__ bar)
{
    __shared__ __align__(16) char smem[98304];   // 96 KB, phase-shared
    const int bid  = blockIdx.x;
    const int tid  = threadIdx.x;
    const int lane = tid & 63;
    const int w    = tid >> 6;
    const int wr   = w >> 1;
    const int wc   = w & 1;
    const int lr   = lane & 15;
    const int kg   = (lane >> 4) * 8;
    const int rg   = (lane >> 4) * 4;
    const int lrow8 = lane >> 3;
    const int lkoff = (lane & 7) * 8;

    // ================= phase 0: prep, byte-balanced ======================
    {
        // xcvt: 4096 jobs of 256 float4. 64 WvT blocks: 14 jobs; 64 WeffT
        // blocks: 6; 128 plain blocks: 22.  64*14 + 64*6 + 128*22 = 4096.
        int j0, nj;
        if (bid < 64)       { j0 = bid * 14;                nj = 14; }
        else if (bid < 128) { j0 = 896 + (bid - 64) * 6;    nj = 6;  }
        else                { j0 = 1280 + (bid - 128) * 22; nj = 22; }
        for (int i = 0; i < nj; ++i) {
            int idx = (j0 + i) * 256 + tid;
            float4 v = reinterpret_cast<const float4*>(x)[idx];
            ushort4 o;
            o.x = f2bf(v.x); o.y = f2bf(v.y);
            o.z = f2bf(v.z); o.w = f2bf(v.w);
            reinterpret_cast<ushort4*>(xb)[idx] = o;
        }

        float (*ld)[65] = (float(*)[65])smem;     // 64x65 f32 = 16.6 KB
        if (bid < 64) {
            // WvT[c][d] = bf16(Wv[d][c]) via 64x64 LDS transpose
            const int d0 = (bid & 15) * 64;
            const int c0 = (bid >> 4) * 64;
            #pragma unroll
            for (int i = 0; i < 4; ++i) {
                int row  = i * 16 + (tid >> 4);
                int col4 = (tid & 15) * 4;
                float4 v = *reinterpret_cast<const float4*>(
                    Wv + (size_t)(d0 + row) * KVDIM + c0 + col4);
                ld[row][col4 + 0] = v.x; ld[row][col4 + 1] = v.y;
                ld[row][col4 + 2] = v.z; ld[row][col4 + 3] = v.w;
            }
            __syncthreads();
            #pragma unroll
            for (int i = 0; i < 4; ++i) {
                int crow = i * 16 + (tid >> 4);
                int dcol = (tid & 15) * 4;
                ushort4 o;
                o.x = f2bf(ld[dcol + 0][crow]);
                o.y = f2bf(ld[dcol + 1][crow]);
                o.z = f2bf(ld[dcol + 2][crow]);
                o.w = f2bf(ld[dcol + 3][crow]);
                *reinterpret_cast<ushort4*>(
                    WvT + (size_t)(c0 + crow) * DMODEL + d0 + dcol) = o;
            }
        } else if (bid < 128) {
            // WeffT[m][c] = bf16(fold(Wo)) via 64(m)x64(c) LDS tile
            const int tile = bid - 64;
            const int m0 = (tile & 15) * 64;
            const int c0 = (tile >> 4) * 64;
            #pragma unroll
            for (int g = 0; g < 16; ++g) {
                int cl = g * 4 + (tid >> 6);
                int ml = tid & 63;
                int c  = c0 + cl;
                const float* bp = Wo
                    + (size_t)((c >> 6) * 256 + (c & 63)) * DMODEL + m0 + ml;
                float s = bp[0] + bp[(size_t)64 * DMODEL]
                        + bp[(size_t)128 * DMODEL]
                        + bp[(size_t)192 * DMODEL];
                ld[cl][ml] = s;
            }
            __syncthreads();
            const int mrow = tid >> 2;
            const int cch  = (tid & 3) * 16;
            #pragma unroll
            for (int jj = 0; jj < 4; ++jj) {
                ushort4 o;
                o.x = f2bf(ld[cch + jj * 4 + 0][mrow]);
                o.y = f2bf(ld[cch + jj * 4 + 1][mrow]);
                o.z = f2bf(ld[cch + jj * 4 + 2][mrow]);
                o.w = f2bf(ld[cch + jj * 4 + 3][mrow]);
                *reinterpret_cast<ushort4*>(
                    WeffT + (size_t)(m0 + mrow) * KVDIM
                          + c0 + cch + jj * 4) = o;
            }
        }
    }
    gbar(bar + 0, NBLK);

    // ================= phase A: Vb = xb @ WvT^T (R9/R11 verbatim) ========
    {
        short* As = (short*)smem;             // 3 x 4096 shorts = 24 KB
        short* Bs = (short*)(smem + 24576);   // 3 x 4096 shorts = 24 KB
        const int swz  = (bid & 7) * 32 + (bid >> 3);
        const int brow = (swz >> 2) * 64;
        const int bcol = (swz & 3) * 64;

        auto stage = [&](int buf, int kt) {
            #pragma unroll
            for (int i = 0; i < 2; ++i) {
                const int ch = w * 2 + i;                   // 0..7
                const unsigned short* g =
                    xb + (size_t)(brow + ch * 8 + lrow8) * DMODEL + kt + lkoff;
                __builtin_amdgcn_global_load_lds(
                    (const __attribute__((address_space(1))) void*)g,
                    (__attribute__((address_space(3))) void*)
                        (As + buf * 4096 + ch * 512),
                    16, 0, 0);
            }
            #pragma unroll
            for (int i = 0; i < 2; ++i) {
                const int ch = w * 2 + i;
                const unsigned short* g =
                    WvT + (size_t)(bcol + ch * 8 + lrow8) * DMODEL + kt + lkoff;
                __builtin_amdgcn_global_load_lds(
                    (const __attribute__((address_space(1))) void*)g,
                    (__attribute__((address_space(3))) void*)
                        (Bs + buf * 4096 + ch * 512),
                    16, 0, 0);
            }
        };

        f32x4 acc[2][2] = {};
        constexpr int nt = DMODEL / 64;       // 16
        stage(0, 0);
        stage(1, 64);
        int bc = 0;
        for (int t = 0; t < nt; ++t) {
            if (t + 1 < nt) asm volatile("s_waitcnt vmcnt(4)" ::: "memory");
            else            asm volatile("s_waitcnt vmcnt(0)" ::: "memory");
            __builtin_amdgcn_s_barrier();

            int bs = bc + 2; if (bs >= 3) bs -= 3;
            if (t + 2 < nt) stage(bs, (t + 2) << 6);

            #pragma unroll
            for (int ks = 0; ks < 2; ++ks) {
                bf16x8 a[2], b[2];
                #pragma unroll
                for (int m = 0; m < 2; ++m)
                    a[m] = *reinterpret_cast<const bf16x8*>(
                        As + bc * 4096
                           + (wr * 32 + m * 16 + lr) * 64 + ks * 32 + kg);
                #pragma unroll
                for (int n = 0; n < 2; ++n)
                    b[n] = *reinterpret_cast<const bf16x8*>(
                        Bs + bc * 4096
                           + (wc * 32 + n * 16 + lr) * 64 + ks * 32 + kg);
                #pragma unroll
                for (int m = 0; m < 2; ++m)
                    #pragma unroll
                    for (int n = 0; n < 2; ++n)
                        acc[m][n] = __builtin_amdgcn_mfma_f32_16x16x32_bf16(
                            a[m], b[n], acc[m][n], 0, 0, 0);
            }
            bc = (bc == 2) ? 0 : bc + 1;
        }
        #pragma unroll
        for (int m = 0; m < 2; ++m)
            #pragma unroll
            for (int n = 0; n < 2; ++n)
                #pragma unroll
                for (int j = 0; j < 4; ++j) {
                    const size_t row = brow + wr * 32 + m * 16 + rg + j;
                    const size_t col = bcol + wc * 32 + n * 16 + lr;
                    Vb[row * KVDIM + col] = f2bf(acc[m][n][j]);
                }
    }
    gbar(bar + 1, NBLK);

    // ====== phase B: out = Vb @ WeffT^T, ONE 128x128 tile per block ======
    // Triple-buffered depth-2, VERIFIED order: vmcnt(8) -> barrier ->
    // stage(t+2) -> compute. LP = 4(A)+4(B) = 8 loads/wave/stage.
    {
        short* As = (short*)smem;             // 3 x 8192 shorts = 48 KB
        short* Bs = (short*)(smem + 49152);   // 3 x 8192 shorts = 48 KB
        const int swz  = (bid & 7) * 32 + (bid >> 3);
        const int brow = (swz >> 3) * 128;    // 32 tile-rows
        const int bcol = (swz & 7) * 128;     // 8 tile-cols

        auto stage = [&](int buf, int kt) {
            #pragma unroll
            for (int i = 0; i < 4; ++i) {                   // A: 16 chunks
                const int ch = w * 4 + i;
                const unsigned short* g =
                    Vb + (size_t)(brow + ch * 8 + lrow8) * KVDIM + kt + lkoff;
                __builtin_amdgcn_global_load_lds(
                    (const __attribute__((address_space(1))) void*)g,
                    (__attribute__((address_space(3))) void*)
                        (As + buf * 8192 + ch * 512),
                    16, 0, 0);
            }
            #pragma unroll
            for (int i = 0; i < 4; ++i) {                   // B: 16 chunks
                const int ch = w * 4 + i;
                const unsigned short* g =
                    WeffT + (size_t)(bcol + ch * 8 + lrow8) * KVDIM
                          + kt + lkoff;
                __builtin_amdgcn_global_load_lds(
                    (const __attribute__((address_space(1))) void*)g,
                    (__attribute__((address_space(3))) void*)
                        (Bs + buf * 8192 + ch * 512),
                    16, 0, 0);
            }
        };

        f32x4 acc[4][4] = {};
        constexpr int nt = KVDIM / 64;        // 4
        stage(0, 0);
        stage(1, 64);
        int bc = 0;
        for (int t = 0; t < nt; ++t) {
            if (t + 1 < nt) asm volatile("s_waitcnt vmcnt(8)" ::: "memory");
            else            asm volatile("s_waitcnt vmcnt(0)" ::: "memory");
            __builtin_amdgcn_s_barrier();

            int bs = bc + 2; if (bs >= 3) bs -= 3;
            if (t + 2 < nt) stage(bs, (t + 2) << 6);

            #pragma unroll
            for (int ks = 0; ks < 2; ++ks) {
                bf16x8 a[4], b[4];
                #pragma unroll
                for (int m = 0; m < 4; ++m)
                    a[m] = *reinterpret_cast<const bf16x8*>(
                        As + bc * 8192
                           + (wr * 64 + m * 16 + lr) * 64 + ks * 32 + kg);
                #pragma unroll
                for (int n = 0; n < 4; ++n)
                    b[n] = *reinterpret_cast<const bf16x8*>(
                        Bs + bc * 8192
                           + (wc * 64 + n * 16 + lr) * 64 + ks * 32 + kg);
                #pragma unroll
                for (int m = 0; m < 4; ++m)
                    #pragma unroll
                    for (int n = 0; n < 4; ++n)
                        acc[m][n] = __builtin_amdgcn_mfma_f32_16x16x32_bf16(
                            a[m], b[n], acc[m][n], 0, 0, 0);
            }
            bc = (bc == 2) ? 0 : bc + 1;
        }

        // Epilogue: LDS bounce per column-half -> coalesced float4 stores.
        float* Cl = reinterpret_cast<float*>(smem);   // [128][65] = 33.3 KB
        #pragma unroll
        for (int h = 0; h < 2; ++h) {
            __syncthreads();                  // LDS free (K-loop/prev half)
            if (wc == h) {
                #pragma unroll
                for (int m = 0; m < 4; ++m)
                    #pragma unroll
                    for (int n = 0; n < 4; ++n)
                        #pragma unroll
                        for (int j = 0; j < 4; ++j)
                            Cl[(wr * 64 + m * 16 + rg + j) * 65
                               + n * 16 + lr] = acc[m][n][j];
            }
            __syncthreads();
            #pragma unroll
            for (int i = 0; i < 8; ++i) {     // 128x64 f32 = 2048 float4
                const int idx = i * 256 + tid;
                const int row = idx >> 4;
                const int c4  = (idx & 15) * 4;
                float4 v;
                v.x = Cl[row * 65 + c4 + 0];
                v.y = Cl[row * 65 + c4 + 1];
                v.z = Cl[row * 65 + c4 + 2];
                v.w = Cl[row * 65 + c4 + 3];
                *reinterpret_cast<float4*>(
                    out + (size_t)(brow + row) * DMODEL
                        + bcol + h * 64 + c4) = v;
            }
        }
    }
}

extern "C" void kernel_launch(void* const* d_in, const int* in_sizes, int n_in,
                              void* d_out, int out_size, void* d_ws, size_t ws_size,
                              hipStream_t stream) {
    const float* x  = (const float*)d_in[0];   // (4096, 1024)
    const float* Wv = (const float*)d_in[3];   // (1024, 256)
    const float* Wo = (const float*)d_in[4];   // (1024, 1024)
    float* out = (float*)d_out;                // (4096, 1024) f32

    unsigned short* xb    = (unsigned short*)d_ws;           // 8 MB
    unsigned short* WvT   = xb    + (size_t)ROWS * DMODEL;   // 0.5 MB [c][d]
    unsigned short* WeffT = WvT   + (size_t)KVDIM * DMODEL;  // 0.5 MB [m][c]
    unsigned short* Vb    = WeffT + (size_t)DMODEL * KVDIM;  // 2 MB   [r][c]
    unsigned*       bar   = (unsigned*)(Vb + (size_t)ROWS * KVDIM);

    hipMemsetAsync(bar, 0, 2 * sizeof(unsigned), stream);
    fused_kernel<<<NBLK, 256, 0, stream>>>(
        x, Wv, Wo, xb, WvT, WeffT, Vb, out, bar);
}

// Round 16
// 37.224 us; speedup vs baseline: 2.1360x; 2.1360x over previous
//
#include <hip/hip_runtime.h>
#include <hip/hip_bf16.h>

// MicrotubuleAttention — exact algebraic reduction + bf16 MFMA.
//
// GTP penalty: (1 - exp(-gamma*dist))*(-1e9), gamma >= 1e-4 => every
// off-diagonal softmax argument <= -9.9e4 => expf underflows to exactly 0.
// Softmax is exactly one-hot at k==q, so attention output == V_rep and
//   out = (x @ Wv) @ Weff        (4.3 GFLOP total)
// with Weff[c][m] = sum_{r=0..3} Wo[(4*(c>>6)+r)*64 + (c&63)][m]  (GQA fold).
// RoPE/Q/K/polarity are dead code.  Pipeline (3 launches):
//   1. prep:  xb = bf16(x); WvT = bf16(Wv^T); WeffT = bf16(fold(Wo)^T)
//             (R9 verbatim — LDS-tile transposes, coalesced R+W)
//   2. Vb    = xb @ WvT^T    [4096,256]  K=1024 — BM=64 x BN=32 -> 512
//             blocks = 2/CU. Pipeline: VERIFIED 2-buffer __syncthreads
//             prefetch (R2/R3 pattern) — no raw-barrier/vmcnt rebuild risk
//             (R13/R15 lesson); the implicit vmcnt(0) drain is covered by
//             the co-resident 2nd block.
//   3. out   = Vb @ WeffT^T  [4096,1024] K=256 (R9 verbatim: triple-buffer
//             counted vmcnt(6), LDS-bounce coalesced f32 epilogue)
// Rules: no f32->bf16 cvt inside GEMM K-loops (R6/R12); grid-barrier fusion
// closed (R7/R10/R11/R14); vmcnt must precede s_barrier (R13).

using bf16x8 = __attribute__((ext_vector_type(8))) short;
using f32x4  = __attribute__((ext_vector_type(4))) float;

static constexpr int DMODEL = 1024;
static constexpr int KVDIM  = 256;   // H_KV * D_HEAD
static constexpr int ROWS   = 4096;  // B * T

__device__ inline unsigned short f2bf(float f) {
    __hip_bfloat16 h = __float2bfloat16(f);   // RNE
    return *reinterpret_cast<unsigned short*>(&h);
}

// ---- fused prep: block-range partitioned (R9 verbatim) -------------------
static constexpr int XCVT_BLOCKS = (ROWS * DMODEL) / 4 / 256;   // 4096
static constexpr int WVT_TILES   = (DMODEL / 64) * (KVDIM / 64);   // 64
static constexpr int WEFF_TILES  = (DMODEL / 64) * (KVDIM / 64);   // 64

__global__ void prep_kernel(const float* __restrict__ x,
                            const float* __restrict__ Wv,
                            const float* __restrict__ Wo,
                            unsigned short* __restrict__ xb,
                            unsigned short* __restrict__ WvT,
                            unsigned short* __restrict__ WeffT) {
    __shared__ float ld[64][65];     // padded: conflict-free column reads
    const int b = blockIdx.x;
    const int t = threadIdx.x;

    if (b < XCVT_BLOCKS) {
        // xb = bf16(x), fully coalesced float4 -> ushort4
        int i = b * 256 + t;
        float4 v = reinterpret_cast<const float4*>(x)[i];
        ushort4 o;
        o.x = f2bf(v.x); o.y = f2bf(v.y); o.z = f2bf(v.z); o.w = f2bf(v.w);
        reinterpret_cast<ushort4*>(xb)[i] = o;
    } else if (b < XCVT_BLOCKS + WVT_TILES) {
        // WvT[c][d] = bf16(Wv[d][c]) via 64x64 LDS transpose tile
        const int tile = b - XCVT_BLOCKS;
        const int d0 = (tile & 15) * 64;
        const int c0 = (tile >> 4) * 64;
        #pragma unroll
        for (int i = 0; i < 4; ++i) {             // coalesced float4 reads
            int row  = i * 16 + (t >> 4);
            int col4 = (t & 15) * 4;
            float4 v = *reinterpret_cast<const float4*>(
                Wv + (size_t)(d0 + row) * KVDIM + c0 + col4);
            ld[row][col4 + 0] = v.x; ld[row][col4 + 1] = v.y;
            ld[row][col4 + 2] = v.z; ld[row][col4 + 3] = v.w;
        }
        __syncthreads();
        #pragma unroll
        for (int i = 0; i < 4; ++i) {             // coalesced ushort4 writes
            int crow = i * 16 + (t >> 4);
            int dcol = (t & 15) * 4;
            ushort4 o;
            o.x = f2bf(ld[dcol + 0][crow]);
            o.y = f2bf(ld[dcol + 1][crow]);
            o.z = f2bf(ld[dcol + 2][crow]);
            o.w = f2bf(ld[dcol + 3][crow]);
            *reinterpret_cast<ushort4*>(
                WvT + (size_t)(c0 + crow) * DMODEL + d0 + dcol) = o;
        }
    } else {
        // WeffT[m][c] = bf16(sum_r Wo[(4*(c>>6)+r)*64 + (c&63)][m])
        const int tile = b - XCVT_BLOCKS - WVT_TILES;
        const int m0 = (tile & 15) * 64;
        const int c0 = (tile >> 4) * 64;
        #pragma unroll
        for (int g = 0; g < 16; ++g) {
            int cl = g * 4 + (t >> 6);
            int ml = t & 63;
            int c  = c0 + cl;
            const float* bp =
                Wo + (size_t)((c >> 6) * 256 + (c & 63)) * DMODEL + m0 + ml;
            float s = bp[0] + bp[(size_t)64 * DMODEL]
                    + bp[(size_t)128 * DMODEL] + bp[(size_t)192 * DMODEL];
            ld[cl][ml] = s;
        }
        __syncthreads();
        const int mrow = t >> 2;
        const int cch  = (t & 3) * 16;
        #pragma unroll
        for (int jj = 0; jj < 4; ++jj) {
            ushort4 o;
            o.x = f2bf(ld[cch + jj * 4 + 0][mrow]);
            o.y = f2bf(ld[cch + jj * 4 + 1][mrow]);
            o.z = f2bf(ld[cch + jj * 4 + 2][mrow]);
            o.w = f2bf(ld[cch + jj * 4 + 3][mrow]);
            *reinterpret_cast<ushort4*>(
                WeffT + (size_t)(m0 + mrow) * KVDIM + c0 + cch + jj * 4) = o;
        }
    }
}

// ---- gemmA: Vb[4096][256] = xb @ WvT^T -----------------------------------
// BM=64, BN=32, BK=64; grid (8,64) = 512 blocks = 2/CU.
// VERIFIED 2-buffer __syncthreads prefetch loop (R2/R3 pattern):
//   syncthreads (drains stage loads, publishes cur) -> stage(cur^1, t+1)
//   -> compute(cur). Cross-block overlap covers the vmcnt(0) drain.
// 4 waves 2x2, wave tile 32x16 (acc[2]).
__launch_bounds__(256, 2)
__global__ void gemm_xwv(const unsigned short* __restrict__ A,
                         const unsigned short* __restrict__ Bt,
                         unsigned short* __restrict__ Vb) {
    constexpr int K = DMODEL;        // 1024
    __shared__ short As[2][64 * 64];    // 2 x 8 KB
    __shared__ short Bs[2][32 * 64];    // 2 x 4 KB

    // T1: XCD-chunked swizzle (nwg = 512)
    const int gx  = gridDim.x;                    // 8
    const int bid = blockIdx.y * gx + blockIdx.x;
    const int cpx = (gx * gridDim.y) >> 3;        // 64
    const int swz = (bid & 7) * cpx + (bid >> 3);
    const int brow = (swz / gx) * 64;
    const int bcol = (swz % gx) * 32;

    const int tid  = threadIdx.x;
    const int lane = tid & 63;
    const int w    = tid >> 6;
    const int wr   = w >> 1;         // 0..1: 32-row half
    const int wc   = w & 1;          // 0..1: 16-col half

    const int lrow8 = lane >> 3;
    const int lkoff = (lane & 7) * 8;
    const int lr    = lane & 15;
    const int kg    = (lane >> 4) * 8;

    f32x4 acc[2] = {};               // AM=2, AN=1

    auto stage = [&](int buf, int kt) {
        #pragma unroll
        for (int i = 0; i < 2; ++i) {                   // A: 8 chunks total
            const int ch = w * 2 + i;
            const unsigned short* g =
                A + (size_t)(brow + ch * 8 + lrow8) * K + kt + lkoff;
            __builtin_amdgcn_global_load_lds(
                (const __attribute__((address_space(1))) void*)g,
                (__attribute__((address_space(3))) void*)(&As[buf][ch * 512]),
                16, 0, 0);
        }
        {                                               // B: 4 chunks total
            const int ch = w;
            const unsigned short* g =
                Bt + (size_t)(bcol + ch * 8 + lrow8) * K + kt + lkoff;
            __builtin_amdgcn_global_load_lds(
                (const __attribute__((address_space(1))) void*)g,
                (__attribute__((address_space(3))) void*)(&Bs[buf][ch * 512]),
                16, 0, 0);
        }
    };

    constexpr int nt = K / 64;       // 16
    stage(0, 0);
    int cur = 0;
    for (int t = 0; t < nt; ++t) {
        __syncthreads();             // vmcnt(0)+barrier: buffer cur ready,
                                     // prev compute's reads of cur^1 done
        if (t + 1 < nt) stage(cur ^ 1, (t + 1) << 6);   // in flight during
                                                        // compute below
        #pragma unroll
        for (int ks = 0; ks < 2; ++ks) {
            bf16x8 a[2], b;
            #pragma unroll
            for (int m = 0; m < 2; ++m)
                a[m] = *reinterpret_cast<const bf16x8*>(
                    &As[cur][(wr * 32 + m * 16 + lr) * 64 + ks * 32 + kg]);
            b = *reinterpret_cast<const bf16x8*>(
                &Bs[cur][(wc * 16 + lr) * 64 + ks * 32 + kg]);
            #pragma unroll
            for (int m = 0; m < 2; ++m)
                acc[m] = __builtin_amdgcn_mfma_f32_16x16x32_bf16(
                    a[m], b, acc[m], 0, 0, 0);
        }
        cur ^= 1;
    }

    // C/D layout: col = lane&15, row = (lane>>4)*4 + reg
    const int rg = (lane >> 4) * 4;
    #pragma unroll
    for (int m = 0; m < 2; ++m)
        #pragma unroll
        for (int j = 0; j < 4; ++j) {
            const size_t row = brow + wr * 32 + m * 16 + rg + j;
            const size_t col = bcol + wc * 16 + lr;
            Vb[row * KVDIM + col] = f2bf(acc[m][j]);
        }
}

// ---- gemmB: out[4096][1024] = Vb @ WeffT^T  (R9 verbatim) ----------------
// BM=128, BN=64, BK=64; triple-buffer depth-2, counted vmcnt(6) BEFORE
// s_barrier; LDS-bounce coalesced f32 epilogue.
__launch_bounds__(256, 2)
__global__ void gemm_vb_weff(const unsigned short* __restrict__ A,
                             const unsigned short* __restrict__ Bt,
                             float* __restrict__ C) {
    constexpr int K = KVDIM;          // 256
    constexpr int N = DMODEL;         // 1024

    __shared__ short As[3][128 * 64];   // 48 KB (reused by epilogue bounce)
    __shared__ short Bs[3][64 * 64];    // 24 KB

    const int gx  = gridDim.x;                    // 16
    const int bid = blockIdx.y * gx + blockIdx.x;
    const int cpx = (gx * gridDim.y) >> 3;        // 64
    const int swz = (bid & 7) * cpx + (bid >> 3);
    const int brow = (swz / gx) * 128;
    const int bcol = (swz % gx) * 64;

    const int tid  = threadIdx.x;
    const int lane = tid & 63;
    const int w    = tid >> 6;
    const int wr   = w >> 1;
    const int wc   = w & 1;

    const int lrow8 = lane >> 3;
    const int lkoff = (lane & 7) * 8;
    const int lr    = lane & 15;
    const int kg    = (lane >> 4) * 8;

    f32x4 acc[4][2] = {};

    auto stage = [&](int buf, int kt) {
        #pragma unroll
        for (int i = 0; i < 4; ++i) {
            const int ch = w * 4 + i;                   // 0..15
            const unsigned short* g =
                A + (size_t)(brow + ch * 8 + lrow8) * K + kt + lkoff;
            __builtin_amdgcn_global_load_lds(
                (const __attribute__((address_space(1))) void*)g,
                (__attribute__((address_space(3))) void*)(&As[buf][ch * 512]),
                16, 0, 0);
        }
        #pragma unroll
        for (int i = 0; i < 2; ++i) {
            const int ch = w * 2 + i;                   // 0..7
            const unsigned short* g =
                Bt + (size_t)(bcol + ch * 8 + lrow8) * K + kt + lkoff;
            __builtin_amdgcn_global_load_lds(
                (const __attribute__((address_space(1))) void*)g,
                (__attribute__((address_space(3))) void*)(&Bs[buf][ch * 512]),
                16, 0, 0);
        }
    };

    constexpr int nt = K / 64;          // 4
    stage(0, 0);
    stage(1, 64);
    int bc = 0;
    for (int t = 0; t < nt; ++t) {
        if (t + 1 < nt) asm volatile("s_waitcnt vmcnt(6)" ::: "memory");
        else            asm volatile("s_waitcnt vmcnt(0)" ::: "memory");
        __builtin_amdgcn_s_barrier();

        int bs = bc + 2; if (bs >= 3) bs -= 3;
        if (t + 2 < nt) stage(bs, (t + 2) << 6);

        #pragma unroll
        for (int ks = 0; ks < 2; ++ks) {
            bf16x8 a[4], b[2];
            #pragma unroll
            for (int m = 0; m < 4; ++m)
                a[m] = *reinterpret_cast<const bf16x8*>(
                    &As[bc][(wr * 64 + m * 16 + lr) * 64 + ks * 32 + kg]);
            #pragma unroll
            for (int n = 0; n < 2; ++n)
                b[n] = *reinterpret_cast<const bf16x8*>(
                    &Bs[bc][(wc * 32 + n * 16 + lr) * 64 + ks * 32 + kg]);
            #pragma unroll
            for (int m = 0; m < 4; ++m)
                #pragma unroll
                for (int n = 0; n < 2; ++n)
                    acc[m][n] = __builtin_amdgcn_mfma_f32_16x16x32_bf16(
                        a[m], b[n], acc[m][n], 0, 0, 0);
        }
        bc = (bc == 2) ? 0 : bc + 1;
    }

    // Epilogue: acc -> LDS [128][65] f32 -> coalesced float4 stores.
    float* Cl = reinterpret_cast<float*>(&As[0][0]);   // 33.3 KB of 48 KB
    __syncthreads();
    const int rg = (lane >> 4) * 4;
    #pragma unroll
    for (int m = 0; m < 4; ++m)
        #pragma unroll
        for (int n = 0; n < 2; ++n)
            #pragma unroll
            for (int j = 0; j < 4; ++j)
                Cl[(wr * 64 + m * 16 + rg + j) * 65
                   + wc * 32 + n * 16 + lr] = acc[m][n][j];
    __syncthreads();
    #pragma unroll
    for (int i = 0; i < 8; ++i) {     // 128x64 f32: 8 float4 per thread
        const int idx = i * 256 + tid;
        const int row = idx >> 4;
        const int c4  = (idx & 15) * 4;
        float4 v;
        v.x = Cl[row * 65 + c4 + 0];
        v.y = Cl[row * 65 + c4 + 1];
        v.z = Cl[row * 65 + c4 + 2];
        v.w = Cl[row * 65 + c4 + 3];
        *reinterpret_cast<float4*>(
            C + (size_t)(brow + row) * N + bcol + c4) = v;
    }
}

extern "C" void kernel_launch(void* const* d_in, const int* in_sizes, int n_in,
                              void* d_out, int out_size, void* d_ws, size_t ws_size,
                              hipStream_t stream) {
    const float* x  = (const float*)d_in[0];   // (4096, 1024)
    const float* Wv = (const float*)d_in[3];   // (1024, 256)
    const float* Wo = (const float*)d_in[4];   // (1024, 1024)
    float* out = (float*)d_out;                // (4096, 1024) f32

    unsigned short* xb    = (unsigned short*)d_ws;           // 8 MB
    unsigned short* WvT   = xb    + (size_t)ROWS * DMODEL;   // 0.5 MB [c][d]
    unsigned short* WeffT = WvT   + (size_t)KVDIM * DMODEL;  // 0.5 MB [m][c]
    unsigned short* Vb    = WeffT + (size_t)DMODEL * KVDIM;  // 2 MB   [r][c]

    prep_kernel<<<XCVT_BLOCKS + WVT_TILES + WEFF_TILES, 256, 0, stream>>>(
        x, Wv, Wo, xb, WvT, WeffT);

    // Vb[r][c] = sum_d xb[r][d] * WvT[c][d]    (M=4096, N=256, K=1024)
    gemm_xwv<<<dim3(KVDIM / 32, ROWS / 64), 256, 0, stream>>>(xb, WvT, Vb);

    // out[r][m] = sum_c Vb[r][c] * WeffT[m][c] (M=4096, N=1024, K=256)
    gemm_vb_weff<<<dim3(DMODEL / 64, ROWS / 128), 256, 0, stream>>>(
        Vb, WeffT, out);
}

// Round 17
// 35.759 us; speedup vs baseline: 2.2235x; 1.0410x over previous
//
#include <hip/hip_runtime.h>
#include <hip/hip_bf16.h>

// MicrotubuleAttention — exact algebraic reduction + bf16 MFMA.
// (R9-verified configuration — session best, 35.4 us.)
//
// GTP penalty: (1 - exp(-gamma*dist))*(-1e9), gamma >= 1e-4 => every
// off-diagonal softmax argument <= -9.9e4 => expf underflows to exactly 0.
// Softmax is exactly one-hot at k==q, so attention output == V_rep and
//   out = (x @ Wv) @ Weff        (4.3 GFLOP total)
// with Weff[c][m] = sum_{r=0..3} Wo[(4*(c>>6)+r)*64 + (c&63)][m]  (GQA fold).
// RoPE/Q/K/polarity are dead code.  Pipeline (3 launches):
//   1. prep:  xb = bf16(x); WvT = bf16(Wv^T); WeffT = bf16(fold(Wo)^T)
//             (LDS-tile transposes: all reads AND writes coalesced)
//   2. Vb    = xb @ WvT^T    (MFMA, bf16 out)  [4096,256]   K=1024
//   3. out   = Vb @ WeffT^T  (MFMA, f32 out)   [4096,1024]  K=256
//             (C-write via LDS bounce -> coalesced float4 stores)
// GEMM loops: triple-buffered LDS, depth-2 prefetch, counted s_waitcnt
// vmcnt(LP) (never 0 mid-loop; vmcnt BEFORE s_barrier), one s_barrier per
// K-step, XCD-chunked swizzle (T1).
//
// Closed avenues (measured this session):
//  - grid-barrier fusion: R7/R10/R11/R14 >= 75us + 30ms spin-tail outlier
//  - f32->bf16 cvt inside GEMM K-loops: R6 +2.4us, R12 +10.5us
//  - T2 LDS swizzle at this 2-phase structure: R8 +4.1us (regime-gated)
//  - gemmA 2 blocks/CU retile: R15 incorrect / R16 +1.8us

using bf16x8 = __attribute__((ext_vector_type(8))) short;
using f32x4  = __attribute__((ext_vector_type(4))) float;

static constexpr int DMODEL = 1024;
static constexpr int KVDIM  = 256;   // H_KV * D_HEAD
static constexpr int ROWS   = 4096;  // B * T

__device__ inline unsigned short f2bf(float f) {
    __hip_bfloat16 h = __float2bfloat16(f);   // RNE
    return *reinterpret_cast<unsigned short*>(&h);
}

// ---- fused prep: block-range partitioned -------------------------------
static constexpr int XCVT_BLOCKS = (ROWS * DMODEL) / 4 / 256;   // 4096
static constexpr int WVT_TILES   = (DMODEL / 64) * (KVDIM / 64);   // 64
static constexpr int WEFF_TILES  = (DMODEL / 64) * (KVDIM / 64);   // 64

__global__ void prep_kernel(const float* __restrict__ x,
                            const float* __restrict__ Wv,
                            const float* __restrict__ Wo,
                            unsigned short* __restrict__ xb,
                            unsigned short* __restrict__ WvT,
                            unsigned short* __restrict__ WeffT) {
    __shared__ float ld[64][65];     // padded: conflict-free column reads
    const int b = blockIdx.x;
    const int t = threadIdx.x;

    if (b < XCVT_BLOCKS) {
        // xb = bf16(x), fully coalesced float4 -> ushort4
        int i = b * 256 + t;
        float4 v = reinterpret_cast<const float4*>(x)[i];
        ushort4 o;
        o.x = f2bf(v.x); o.y = f2bf(v.y); o.z = f2bf(v.z); o.w = f2bf(v.w);
        reinterpret_cast<ushort4*>(xb)[i] = o;
    } else if (b < XCVT_BLOCKS + WVT_TILES) {
        // WvT[c][d] = bf16(Wv[d][c]) via 64x64 LDS transpose tile
        const int tile = b - XCVT_BLOCKS;
        const int d0 = (tile & 15) * 64;          // 16 tiles along d
        const int c0 = (tile >> 4) * 64;          // 4 tiles along c
        #pragma unroll
        for (int i = 0; i < 4; ++i) {             // coalesced float4 reads
            int row  = i * 16 + (t >> 4);         // d-local
            int col4 = (t & 15) * 4;              // c-local
            float4 v = *reinterpret_cast<const float4*>(
                Wv + (size_t)(d0 + row) * KVDIM + c0 + col4);
            ld[row][col4 + 0] = v.x; ld[row][col4 + 1] = v.y;
            ld[row][col4 + 2] = v.z; ld[row][col4 + 3] = v.w;
        }
        __syncthreads();
        #pragma unroll
        for (int i = 0; i < 4; ++i) {             // coalesced ushort4 writes
            int crow = i * 16 + (t >> 4);         // c-local
            int dcol = (t & 15) * 4;              // d-local
            ushort4 o;
            o.x = f2bf(ld[dcol + 0][crow]);
            o.y = f2bf(ld[dcol + 1][crow]);
            o.z = f2bf(ld[dcol + 2][crow]);
            o.w = f2bf(ld[dcol + 3][crow]);
            *reinterpret_cast<ushort4*>(
                WvT + (size_t)(c0 + crow) * DMODEL + d0 + dcol) = o;
        }
    } else {
        // WeffT[m][c] = bf16(sum_r Wo[(4*(c>>6)+r)*64 + (c&63)][m])
        // via 64(m) x 64(c) LDS tile: coalesced reads + coalesced writes
        const int tile = b - XCVT_BLOCKS - WVT_TILES;
        const int m0 = (tile & 15) * 64;          // 16 tiles along m
        const int c0 = (tile >> 4) * 64;          // 4 tiles along c
        #pragma unroll
        for (int g = 0; g < 16; ++g) {            // 4 c's per pass
            int cl = g * 4 + (t >> 6);            // c-local
            int ml = t & 63;                      // m-local
            int c  = c0 + cl;
            const float* bp =
                Wo + (size_t)((c >> 6) * 256 + (c & 63)) * DMODEL + m0 + ml;
            float s = bp[0] + bp[(size_t)64 * DMODEL]
                    + bp[(size_t)128 * DMODEL] + bp[(size_t)192 * DMODEL];
            ld[cl][ml] = s;                       // [c-local][m-local]
        }
        __syncthreads();
        const int mrow = t >> 2;                  // m-local row
        const int cch  = (t & 3) * 16;            // c-local 16-chunk
        #pragma unroll
        for (int jj = 0; jj < 4; ++jj) {
            ushort4 o;
            o.x = f2bf(ld[cch + jj * 4 + 0][mrow]);
            o.y = f2bf(ld[cch + jj * 4 + 1][mrow]);
            o.z = f2bf(ld[cch + jj * 4 + 2][mrow]);
            o.w = f2bf(ld[cch + jj * 4 + 3][mrow]);
            *reinterpret_cast<ushort4*>(
                WeffT + (size_t)(m0 + mrow) * KVDIM + c0 + cch + jj * 4) = o;
        }
    }
}

// ---- gemmA: Vb[4096][256] = xb @ WvT^T -----------------------------------
// BM=BN=64, BK=64; 4 waves 2x2, wave tile 32x32. Triple-buffered LDS,
// depth-2 prefetch, counted vmcnt(4), one s_barrier per K-step.
__launch_bounds__(256, 2)
__global__ void gemm_xwv(const unsigned short* __restrict__ A,
                         const unsigned short* __restrict__ Bt,
                         unsigned short* __restrict__ Vb) {
    constexpr int K = DMODEL;        // 1024
    __shared__ short As[3][64 * 64];
    __shared__ short Bs[3][64 * 64];

    const int gx  = gridDim.x;                    // 4
    const int bid = blockIdx.y * gx + blockIdx.x;
    const int cpx = (gx * gridDim.y) >> 3;        // 32
    const int swz = (bid & 7) * cpx + (bid >> 3);
    const int brow = (swz / gx) * 64;
    const int bcol = (swz % gx) * 64;

    const int tid  = threadIdx.x;
    const int lane = tid & 63;
    const int w    = tid >> 6;
    const int wr   = w >> 1;
    const int wc   = w & 1;

    const int lrow8 = lane >> 3;
    const int lkoff = (lane & 7) * 8;
    const int lr    = lane & 15;
    const int kg    = (lane >> 4) * 8;

    f32x4 acc[2][2] = {};

    auto stage = [&](int buf, int kt) {
        #pragma unroll
        for (int i = 0; i < 2; ++i) {
            const int ch = w * 2 + i;                   // 0..7
            const unsigned short* g =
                A + (size_t)(brow + ch * 8 + lrow8) * K + kt + lkoff;
            __builtin_amdgcn_global_load_lds(
                (const __attribute__((address_space(1))) void*)g,
                (__attribute__((address_space(3))) void*)(&As[buf][ch * 512]),
                16, 0, 0);
        }
        #pragma unroll
        for (int i = 0; i < 2; ++i) {
            const int ch = w * 2 + i;
            const unsigned short* g =
                Bt + (size_t)(bcol + ch * 8 + lrow8) * K + kt + lkoff;
            __builtin_amdgcn_global_load_lds(
                (const __attribute__((address_space(1))) void*)g,
                (__attribute__((address_space(3))) void*)(&Bs[buf][ch * 512]),
                16, 0, 0);
        }
    };

    constexpr int nt = K / 64;       // 16
    stage(0, 0);
    stage(1, 64);
    int bc = 0;
    for (int t = 0; t < nt; ++t) {
        if (t + 1 < nt) asm volatile("s_waitcnt vmcnt(4)" ::: "memory");
        else            asm volatile("s_waitcnt vmcnt(0)" ::: "memory");
        __builtin_amdgcn_s_barrier();

        int bs = bc + 2; if (bs >= 3) bs -= 3;
        if (t + 2 < nt) stage(bs, (t + 2) << 6);

        #pragma unroll
        for (int ks = 0; ks < 2; ++ks) {
            bf16x8 a[2], b[2];
            #pragma unroll
            for (int m = 0; m < 2; ++m)
                a[m] = *reinterpret_cast<const bf16x8*>(
                    &As[bc][(wr * 32 + m * 16 + lr) * 64 + ks * 32 + kg]);
            #pragma unroll
            for (int n = 0; n < 2; ++n)
                b[n] = *reinterpret_cast<const bf16x8*>(
                    &Bs[bc][(wc * 32 + n * 16 + lr) * 64 + ks * 32 + kg]);
            #pragma unroll
            for (int m = 0; m < 2; ++m)
                #pragma unroll
                for (int n = 0; n < 2; ++n)
                    acc[m][n] = __builtin_amdgcn_mfma_f32_16x16x32_bf16(
                        a[m], b[n], acc[m][n], 0, 0, 0);
        }
        bc = (bc == 2) ? 0 : bc + 1;
    }

    const int rg = (lane >> 4) * 4;
    #pragma unroll
    for (int m = 0; m < 2; ++m)
        #pragma unroll
        for (int n = 0; n < 2; ++n)
            #pragma unroll
            for (int j = 0; j < 4; ++j) {
                const size_t row = brow + wr * 32 + m * 16 + rg + j;
                const size_t col = bcol + wc * 32 + n * 16 + lr;
                Vb[row * KVDIM + col] = f2bf(acc[m][n][j]);
            }
}

// ---- gemmB: out[4096][1024] = Vb @ WeffT^T ------------------------------
// BM=128, BN=64, BK=64 + LDS-bounce coalesced f32 epilogue.
__launch_bounds__(256, 2)
__global__ void gemm_vb_weff(const unsigned short* __restrict__ A,
                             const unsigned short* __restrict__ Bt,
                             float* __restrict__ C) {
    constexpr int K = KVDIM;          // 256
    constexpr int N = DMODEL;         // 1024

    __shared__ short As[3][128 * 64];   // 48 KB (reused by epilogue bounce)
    __shared__ short Bs[3][64 * 64];    // 24 KB

    const int gx  = gridDim.x;                    // 16
    const int bid = blockIdx.y * gx + blockIdx.x;
    const int cpx = (gx * gridDim.y) >> 3;        // 64
    const int swz = (bid & 7) * cpx + (bid >> 3);
    const int brow = (swz / gx) * 128;
    const int bcol = (swz % gx) * 64;

    const int tid  = threadIdx.x;
    const int lane = tid & 63;
    const int w    = tid >> 6;
    const int wr   = w >> 1;
    const int wc   = w & 1;

    const int lrow8 = lane >> 3;
    const int lkoff = (lane & 7) * 8;
    const int lr    = lane & 15;
    const int kg    = (lane >> 4) * 8;

    f32x4 acc[4][2] = {};

    auto stage = [&](int buf, int kt) {
        #pragma unroll
        for (int i = 0; i < 4; ++i) {
            const int ch = w * 4 + i;                   // 0..15
            const unsigned short* g =
                A + (size_t)(brow + ch * 8 + lrow8) * K + kt + lkoff;
            __builtin_amdgcn_global_load_lds(
                (const __attribute__((address_space(1))) void*)g,
                (__attribute__((address_space(3))) void*)(&As[buf][ch * 512]),
                16, 0, 0);
        }
        #pragma unroll
        for (int i = 0; i < 2; ++i) {
            const int ch = w * 2 + i;                   // 0..7
            const unsigned short* g =
                Bt + (size_t)(bcol + ch * 8 + lrow8) * K + kt + lkoff;
            __builtin_amdgcn_global_load_lds(
                (const __attribute__((address_space(1))) void*)g,
                (__attribute__((address_space(3))) void*)(&Bs[buf][ch * 512]),
                16, 0, 0);
        }
    };

    constexpr int nt = K / 64;          // 4
    stage(0, 0);
    stage(1, 64);
    int bc = 0;
    for (int t = 0; t < nt; ++t) {
        if (t + 1 < nt) asm volatile("s_waitcnt vmcnt(6)" ::: "memory");
        else            asm volatile("s_waitcnt vmcnt(0)" ::: "memory");
        __builtin_amdgcn_s_barrier();

        int bs = bc + 2; if (bs >= 3) bs -= 3;
        if (t + 2 < nt) stage(bs, (t + 2) << 6);

        #pragma unroll
        for (int ks = 0; ks < 2; ++ks) {
            bf16x8 a[4], b[2];
            #pragma unroll
            for (int m = 0; m < 4; ++m)
                a[m] = *reinterpret_cast<const bf16x8*>(
                    &As[bc][(wr * 64 + m * 16 + lr) * 64 + ks * 32 + kg]);
            #pragma unroll
            for (int n = 0; n < 2; ++n)
                b[n] = *reinterpret_cast<const bf16x8*>(
                    &Bs[bc][(wc * 32 + n * 16 + lr) * 64 + ks * 32 + kg]);
            #pragma unroll
            for (int m = 0; m < 4; ++m)
                #pragma unroll
                for (int n = 0; n < 2; ++n)
                    acc[m][n] = __builtin_amdgcn_mfma_f32_16x16x32_bf16(
                        a[m], b[n], acc[m][n], 0, 0, 0);
        }
        bc = (bc == 2) ? 0 : bc + 1;
    }

    // Epilogue: acc -> LDS [128][65] f32 -> coalesced float4 stores.
    float* Cl = reinterpret_cast<float*>(&As[0][0]);   // 33.3 KB of 48 KB
    __syncthreads();                  // K-loop LDS reads complete everywhere
    const int rg = (lane >> 4) * 4;
    #pragma unroll
    for (int m = 0; m < 4; ++m)
        #pragma unroll
        for (int n = 0; n < 2; ++n)
            #pragma unroll
            for (int j = 0; j < 4; ++j)
                Cl[(wr * 64 + m * 16 + rg + j) * 65
                   + wc * 32 + n * 16 + lr] = acc[m][n][j];
    __syncthreads();
    #pragma unroll
    for (int i = 0; i < 8; ++i) {     // 128x64 f32: 8 float4 per thread
        const int idx = i * 256 + tid;
        const int row = idx >> 4;
        const int c4  = (idx & 15) * 4;
        float4 v;
        v.x = Cl[row * 65 + c4 + 0];
        v.y = Cl[row * 65 + c4 + 1];
        v.z = Cl[row * 65 + c4 + 2];
        v.w = Cl[row * 65 + c4 + 3];
        *reinterpret_cast<float4*>(
            C + (size_t)(brow + row) * N + bcol + c4) = v;
    }
}

extern "C" void kernel_launch(void* const* d_in, const int* in_sizes, int n_in,
                              void* d_out, int out_size, void* d_ws, size_t ws_size,
                              hipStream_t stream) {
    const float* x  = (const float*)d_in[0];   // (4096, 1024)
    const float* Wv = (const float*)d_in[3];   // (1024, 256)
    const float* Wo = (const float*)d_in[4];   // (1024, 1024)
    float* out = (float*)d_out;                // (4096, 1024) f32

    unsigned short* xb    = (unsigned short*)d_ws;           // 8 MB
    unsigned short* WvT   = xb    + (size_t)ROWS * DMODEL;   // 0.5 MB [c][d]
    unsigned short* WeffT = WvT   + (size_t)KVDIM * DMODEL;  // 0.5 MB [m][c]
    unsigned short* Vb    = WeffT + (size_t)DMODEL * KVDIM;  // 2 MB   [r][c]

    prep_kernel<<<XCVT_BLOCKS + WVT_TILES + WEFF_TILES, 256, 0, stream>>>(
        x, Wv, Wo, xb, WvT, WeffT);

    // Vb[r][c] = sum_d xb[r][d] * WvT[c][d]    (M=4096, N=256, K=1024)
    gemm_xwv<<<dim3(KVDIM / 64, ROWS / 64), 256, 0, stream>>>(xb, WvT, Vb);

    // out[r][m] = sum_c Vb[r][c] * WeffT[m][c] (M=4096, N=1024, K=256)
    gemm_vb_weff<<<dim3(DMODEL / 64, ROWS / 128), 256, 0, stream>>>(
        Vb, WeffT, out);
}